// Round 10
// baseline (213.556 us; speedup 1.0000x reference)
//
#include <hip/hip_runtime.h>
#include <hip/hip_bf16.h>

typedef unsigned short ushort_t;
typedef __attribute__((ext_vector_type(8))) short bf16x8;
typedef __attribute__((ext_vector_type(4))) float f32x4;

__device__ __forceinline__ ushort_t f2bf(float f) {
    union { float f; unsigned u; } v; v.f = f;
    unsigned r = v.u + 0x7FFF + ((v.u >> 16) & 1);
    return (ushort_t)(r >> 16);
}
__device__ __forceinline__ bf16x8 ld8(const ushort_t* p) { return *(const bf16x8*)p; }

__device__ __forceinline__ unsigned cvt2(float x, float y) {
    __hip_bfloat162 h = __float22bfloat162_rn(make_float2(x, y));
    unsigned r; __builtin_memcpy(&r, &h, 4); return r;
}
__device__ __forceinline__ bf16x8 pack8f(float4 a, float4 b) {
    union { unsigned u[4]; bf16x8 v; } o;
    o.u[0] = cvt2(a.x, a.y); o.u[1] = cvt2(a.z, a.w);
    o.u[2] = cvt2(b.x, b.y); o.u[3] = cvt2(b.z, b.w);
    return o.v;
}

// ---------------------------------------------------------------------------
// Fused QKV projection. grid (4, 64, 3) = 768 blocks (3/CU). 64x128 tile,
// BK=64, pipelined. A and W both fp32, converted in-register.
// z=0: Q*C1 bf16 [m][n]  (C1 = 0.125*log2e folded in);  z=1: K bf16 [m][n];
// z=2: V^T sigma-permuted bf16: dst[((b*8+h)*64+d)*2048 + (s&~127)+8*f+a].
// LDS stride 72: 16B rows, frag reads 2-way banks (free).
// ---------------------------------------------------------------------------
__global__ __launch_bounds__(256, 3)
void proj_qkv_kernel(const float* __restrict__ Qe, const float* __restrict__ Ke,
                     const float* __restrict__ x,
                     const float* __restrict__ Wq, const float* __restrict__ Wk,
                     const float* __restrict__ Wv,
                     const float* __restrict__ bq, const float* __restrict__ bk,
                     const float* __restrict__ bv,
                     ushort_t* __restrict__ Qo, ushort_t* __restrict__ Ko,
                     ushort_t* __restrict__ Vt)
{
    __shared__ ushort_t lA[64 * 72];
    __shared__ ushort_t lB[128 * 72];
    const int z = blockIdx.z;
    const float* A = (z == 0) ? Qe : (z == 1) ? Ke : x;
    const float* W = (z == 0) ? Wq : (z == 1) ? Wk : Wv;
    const float* bias = (z == 0) ? bq : (z == 1) ? bk : bv;

    const int m0 = blockIdx.y * 64, n0 = blockIdx.x * 128;
    const int t = threadIdx.x;
    const int lane = t & 63, wave = t >> 6;
    const int wm = (wave & 1) * 32, wn = (wave >> 1) * 64;
    const int fr = lane & 15, quad = lane >> 4;

    f32x4 acc[2][4] = {};
    float4 fa[2][2], fw[4][2];

    // prologue: loads for k0 = 0
#pragma unroll
    for (int i = 0; i < 2; ++i) {
        int s = i * 256 + t;
        int r = s >> 3, jp = s & 7;
        const float* p = A + (size_t)(m0 + r) * 512 + jp * 8;
        fa[i][0] = *(const float4*)p; fa[i][1] = *(const float4*)(p + 4);
    }
#pragma unroll
    for (int i = 0; i < 4; ++i) {
        int s = i * 256 + t;
        int r = s >> 3, jp = s & 7;
        const float* p = W + (size_t)(n0 + r) * 512 + jp * 8;
        fw[i][0] = *(const float4*)p; fw[i][1] = *(const float4*)(p + 4);
    }

    for (int kk = 0; kk < 8; ++kk) {
        if (kk) __syncthreads();
#pragma unroll
        for (int i = 0; i < 2; ++i) {
            int s = i * 256 + t;
            int r = s >> 3, jp = s & 7;
            *(bf16x8*)(lA + r * 72 + jp * 8) = pack8f(fa[i][0], fa[i][1]);
        }
#pragma unroll
        for (int i = 0; i < 4; ++i) {
            int s = i * 256 + t;
            int r = s >> 3, jp = s & 7;
            *(bf16x8*)(lB + r * 72 + jp * 8) = pack8f(fw[i][0], fw[i][1]);
        }
        __syncthreads();
        if (kk < 7) {
            int k0 = (kk + 1) * 64;
#pragma unroll
            for (int i = 0; i < 2; ++i) {
                int s = i * 256 + t;
                int r = s >> 3, jp = s & 7;
                const float* p = A + (size_t)(m0 + r) * 512 + k0 + jp * 8;
                fa[i][0] = *(const float4*)p; fa[i][1] = *(const float4*)(p + 4);
            }
#pragma unroll
            for (int i = 0; i < 4; ++i) {
                int s = i * 256 + t;
                int r = s >> 3, jp = s & 7;
                const float* p = W + (size_t)(n0 + r) * 512 + k0 + jp * 8;
                fw[i][0] = *(const float4*)p; fw[i][1] = *(const float4*)(p + 4);
            }
        }

        bf16x8 af[2][2], bfrag[4][2];
#pragma unroll
        for (int ks = 0; ks < 2; ++ks) {
#pragma unroll
            for (int mt = 0; mt < 2; ++mt)
                af[mt][ks] = ld8(lA + (wm + mt * 16 + fr) * 72 + (ks * 4 + quad) * 8);
#pragma unroll
            for (int nt = 0; nt < 4; ++nt)
                bfrag[nt][ks] = ld8(lB + (wn + nt * 16 + fr) * 72 + (ks * 4 + quad) * 8);
        }
#pragma unroll
        for (int ks = 0; ks < 2; ++ks)
#pragma unroll
            for (int mt = 0; mt < 2; ++mt)
#pragma unroll
                for (int nt = 0; nt < 4; ++nt)
                    acc[mt][nt] = __builtin_amdgcn_mfma_f32_16x16x32_bf16(
                        af[mt][ks], bfrag[nt][ks], acc[mt][nt], 0, 0, 0);
    }

    const float C1 = 0.125f * 1.44269504088896340736f;
    // C/D: col = lane&15, row = quad*4 + reg (measured m89/m91).
#pragma unroll
    for (int nt = 0; nt < 4; ++nt) {
        int n = n0 + wn + nt * 16 + fr;
        float bb = bias[n];
#pragma unroll
        for (int mt = 0; mt < 2; ++mt) {
            int mb = m0 + wm + mt * 16 + quad * 4;
            if (z == 0) {
#pragma unroll
                for (int r = 0; r < 4; ++r)
                    Qo[(size_t)(mb + r) * 512 + n] = f2bf((acc[mt][nt][r] + bb) * C1);
            } else if (z == 1) {
#pragma unroll
                for (int r = 0; r < 4; ++r)
                    Ko[(size_t)(mb + r) * 512 + n] = f2bf(acc[mt][nt][r] + bb);
            } else {
                int h = n >> 6, d = n & 63;
                int bidx = mb >> 11;
                int st = mb & 2047;
                int a = (st >> 4) & 7;            // sigma: s' = (st&~127) + 8*f + a
                size_t base = ((size_t)((bidx * 8 + h) * 64 + d)) * 2048 + (st & ~127) + a;
#pragma unroll
                for (int r = 0; r < 4; ++r)
                    Vt[base + (size_t)(quad * 4 + r) * 8] = f2bf(acc[mt][nt][r] + bb);
            }
        }
    }
}

// ---------------------------------------------------------------------------
// O-projection: 64x64 tile, grid (8,64) = 512 blocks (2/CU), BK=64, pipelined.
// A bf16, W fp32 (in-register pack).
// ---------------------------------------------------------------------------
__global__ __launch_bounds__(256, 2)
void gemm_o_kernel(const ushort_t* __restrict__ A, const float* __restrict__ W,
                   const float* __restrict__ bias, float* __restrict__ dst)
{
    __shared__ ushort_t lA[64 * 72];
    __shared__ ushort_t lB[64 * 72];
    const int m0 = blockIdx.y * 64, n0 = blockIdx.x * 64;
    const int t = threadIdx.x;
    const int lane = t & 63, wave = t >> 6;
    const int wm = (wave & 1) * 32, wn = (wave >> 1) * 32;
    const int fr = lane & 15, quad = lane >> 4;

    f32x4 acc[2][2] = {};
    bf16x8 va[2];
    float4 fw[2][2];

#pragma unroll
    for (int i = 0; i < 2; ++i) {
        int s = i * 256 + t;
        int r = s >> 3, jp = s & 7;
        va[i] = ld8(A + (size_t)(m0 + r) * 512 + jp * 8);
        const float* p = W + (size_t)(n0 + r) * 512 + jp * 8;
        fw[i][0] = *(const float4*)p; fw[i][1] = *(const float4*)(p + 4);
    }

    for (int kk = 0; kk < 8; ++kk) {
        if (kk) __syncthreads();
#pragma unroll
        for (int i = 0; i < 2; ++i) {
            int s = i * 256 + t;
            int r = s >> 3, jp = s & 7;
            *(bf16x8*)(lA + r * 72 + jp * 8) = va[i];
            *(bf16x8*)(lB + r * 72 + jp * 8) = pack8f(fw[i][0], fw[i][1]);
        }
        __syncthreads();
        if (kk < 7) {
            int k0 = (kk + 1) * 64;
#pragma unroll
            for (int i = 0; i < 2; ++i) {
                int s = i * 256 + t;
                int r = s >> 3, jp = s & 7;
                va[i] = ld8(A + (size_t)(m0 + r) * 512 + k0 + jp * 8);
                const float* p = W + (size_t)(n0 + r) * 512 + k0 + jp * 8;
                fw[i][0] = *(const float4*)p; fw[i][1] = *(const float4*)(p + 4);
            }
        }

        bf16x8 af[2][2], bfrag[2][2];
#pragma unroll
        for (int ks = 0; ks < 2; ++ks) {
#pragma unroll
            for (int mt = 0; mt < 2; ++mt)
                af[mt][ks] = ld8(lA + (wm + mt * 16 + fr) * 72 + (ks * 4 + quad) * 8);
#pragma unroll
            for (int nt = 0; nt < 2; ++nt)
                bfrag[nt][ks] = ld8(lB + (wn + nt * 16 + fr) * 72 + (ks * 4 + quad) * 8);
        }
#pragma unroll
        for (int ks = 0; ks < 2; ++ks)
#pragma unroll
            for (int mt = 0; mt < 2; ++mt)
#pragma unroll
                for (int nt = 0; nt < 2; ++nt)
                    acc[mt][nt] = __builtin_amdgcn_mfma_f32_16x16x32_bf16(
                        af[mt][ks], bfrag[nt][ks], acc[mt][nt], 0, 0, 0);
    }

#pragma unroll
    for (int nt = 0; nt < 2; ++nt) {
        int n = n0 + wn + nt * 16 + fr;
        float bb = bias[n];
#pragma unroll
        for (int mt = 0; mt < 2; ++mt) {
            int mb = m0 + wm + mt * 16 + quad * 4;
#pragma unroll
            for (int r = 0; r < 4; ++r)
                dst[(size_t)(mb + r) * 512 + n] = acc[mt][nt][r] + bb;
        }
    }
}

// ---------------------------------------------------------------------------
// Single-pass flash attention, no-max softmax (C1 folded into Q).
// 128-thread blocks: 2 waves x 32 q-rows (halves wave-redundant kb/vb reads:
// 192 -> 128 DS instrs per block-iter; DS-pipe model 20.5 us).
// Grid (32,8,2) = 512 blocks; q-tile 64; KV-tile 128; LDS 53 KB.
// sigma-permuted key order in lP/lVt (b128 P-writes).
// ---------------------------------------------------------------------------
__global__ __launch_bounds__(128, 2)
void attn_kernel(const ushort_t* __restrict__ Q, const ushort_t* __restrict__ K,
                 const ushort_t* __restrict__ Vt, ushort_t* __restrict__ O)
{
    __shared__ ushort_t lK[128 * 72];
    __shared__ ushort_t lVt[64 * 136];   // [d][key-sigma]
    __shared__ ushort_t lP[64 * 136];    // [q][key-sigma], wave-local rows

    const int b = blockIdx.z, h = blockIdx.y;
    const int q0 = blockIdx.x * 64;
    const int t = threadIdx.x;
    const int lane = t & 63, wave = t >> 6;   // wave in {0,1}
    const int wq = wave * 32;
    const int fr = lane & 15, quad = lane >> 4;

    // Q fragments (32 rows/wave -> 2 mt x 2 ks) from global, register-resident.
    bf16x8 aq[2][2];
#pragma unroll
    for (int mt = 0; mt < 2; ++mt) {
        const ushort_t* qp = Q + (size_t)(b * 2048 + q0 + wq + mt * 16 + fr) * 512
                             + h * 64 + quad * 8;
        aq[mt][0] = ld8(qp);
        aq[mt][1] = ld8(qp + 32);
    }

    f32x4 oacc[2][4] = {};
    float lpart[2][4] = {};
    bf16x8 vk[8], vv[8];

    // prologue: loads for kv = 0 (128 threads -> 8 chunks each)
#pragma unroll
    for (int i = 0; i < 8; ++i) {
        int s = i * 128 + t;
        int r = s >> 3, jp = s & 7;
        vk[i] = ld8(K + (size_t)(b * 2048 + r) * 512 + h * 64 + jp * 8);
        int r2 = s >> 4, jp2 = s & 15;
        vv[i] = ld8(Vt + (size_t)((b * 8 + h) * 64 + r2) * 2048 + jp2 * 8);
    }

    for (int kv = 0; kv < 2048; kv += 128) {
        if (kv) __syncthreads();   // prev iter's lK/lVt reads done
#pragma unroll
        for (int i = 0; i < 8; ++i) {
            int s = i * 128 + t;
            int r = s >> 3, jp = s & 7;
            *(bf16x8*)(lK + r * 72 + jp * 8) = vk[i];
            int r2 = s >> 4, jp2 = s & 15;
            *(bf16x8*)(lVt + r2 * 136 + jp2 * 8) = vv[i];
        }
        __syncthreads();
        if (kv + 128 < 2048) {           // prefetch next tile during compute
            int kn = kv + 128;
#pragma unroll
            for (int i = 0; i < 8; ++i) {
                int s = i * 128 + t;
                int r = s >> 3, jp = s & 7;
                vk[i] = ld8(K + (size_t)(b * 2048 + kn + r) * 512 + h * 64 + jp * 8);
                int r2 = s >> 4, jp2 = s & 15;
                vv[i] = ld8(Vt + (size_t)((b * 8 + h) * 64 + r2) * 2048 + kn + jp2 * 8);
            }
        }

        // S = Q K^T : wave's 32 q-rows x 128 keys; each kb feeds 2 MFMAs.
        f32x4 sc[2][8] = {};
#pragma unroll
        for (int ks = 0; ks < 2; ++ks)
#pragma unroll
            for (int nt = 0; nt < 8; ++nt) {
                bf16x8 kb = ld8(lK + (nt * 16 + fr) * 72 + (ks * 4 + quad) * 8);
#pragma unroll
                for (int mt = 0; mt < 2; ++mt)
                    sc[mt][nt] = __builtin_amdgcn_mfma_f32_16x16x32_bf16(
                        aq[mt][ks], kb, sc[mt][nt], 0, 0, 0);
            }

        // No-max softmax: p = exp2(sc); P sigma-ordered, one b128 write per row.
#pragma unroll
        for (int mt = 0; mt < 2; ++mt)
#pragma unroll
            for (int r = 0; r < 4; ++r) {
                int row = wq + mt * 16 + quad * 4 + r;
                float pv[8];
                float acc = 0.f;
#pragma unroll
                for (int nt = 0; nt < 8; ++nt) {
                    pv[nt] = exp2f(sc[mt][nt][r]);
                    acc += pv[nt];
                }
                lpart[mt][r] += acc;
                union { unsigned u[4]; bf16x8 v; } pu;
                pu.u[0] = cvt2(pv[0], pv[1]); pu.u[1] = cvt2(pv[2], pv[3]);
                pu.u[2] = cvt2(pv[4], pv[5]); pu.u[3] = cvt2(pv[6], pv[7]);
                *(bf16x8*)(lP + row * 136 + fr * 8) = pu.v;
            }
        // lP rows wave-local; in-wave DS ordering suffices (verified r5-r9).

        // O += P V  (both operands in sigma key order); each vb feeds 2 MFMAs.
#pragma unroll
        for (int ks = 0; ks < 4; ++ks) {
            bf16x8 ap[2];
#pragma unroll
            for (int mt = 0; mt < 2; ++mt)
                ap[mt] = ld8(lP + (wq + mt * 16 + fr) * 136 + ks * 32 + quad * 8);
#pragma unroll
            for (int nt = 0; nt < 4; ++nt) {
                bf16x8 vb = ld8(lVt + (nt * 16 + fr) * 136 + ks * 32 + quad * 8);
#pragma unroll
                for (int mt = 0; mt < 2; ++mt)
                    oacc[mt][nt] = __builtin_amdgcn_mfma_f32_16x16x32_bf16(
                        ap[mt], vb, oacc[mt][nt], 0, 0, 0);
            }
        }
    }

    // Epilogue: reduce l over the 16 lanes of each row, O = oacc / l.
#pragma unroll
    for (int mt = 0; mt < 2; ++mt)
#pragma unroll
        for (int r = 0; r < 4; ++r) {
            float rs = lpart[mt][r];
#pragma unroll
            for (int o = 1; o < 16; o <<= 1)
                rs += __shfl_xor(rs, o, 64);
            float inv = 1.f / rs;
            int q = q0 + wq + mt * 16 + quad * 4 + r;
#pragma unroll
            for (int nt = 0; nt < 4; ++nt) {
                int d = nt * 16 + fr;
                O[(size_t)(b * 2048 + q) * 512 + h * 64 + d] = f2bf(oacc[mt][nt][r] * inv);
            }
        }
}

extern "C" void kernel_launch(void* const* d_in, const int* in_sizes, int n_in,
                              void* d_out, int out_size, void* d_ws, size_t ws_size,
                              hipStream_t stream) {
    const float* x   = (const float*)d_in[0];
    const float* Qe  = (const float*)d_in[1];
    const float* Ke  = (const float*)d_in[2];
    // d_in[3..6] scalars unused (drofe_fn is None in reference)
    const float* Wq  = (const float*)d_in[7];
    const float* bq  = (const float*)d_in[8];
    const float* Wk  = (const float*)d_in[9];
    const float* bk  = (const float*)d_in[10];
    const float* Wv  = (const float*)d_in[11];
    const float* bv  = (const float*)d_in[12];
    const float* Wo  = (const float*)d_in[13];
    const float* bo  = (const float*)d_in[14];

    const size_t NTOK = 2 * 2048;
    const size_t ACT = NTOK * 512;

    ushort_t* p = (ushort_t*)d_ws;
    ushort_t* Qws = p; p += ACT;           // [B,S,512], pre-scaled by C1
    ushort_t* Kws = p; p += ACT;           // [B,S,512]
    ushort_t* Vt  = p; p += ACT;           // [B,H,64,S] sigma-permuted per 128
    ushort_t* Ows = p; p += ACT;           // [B,S,512]

    proj_qkv_kernel<<<dim3(4, 64, 3), 256, 0, stream>>>(Qe, Ke, x, Wq, Wk, Wv,
                                                        bq, bk, bv, Qws, Kws, Vt);
    attn_kernel<<<dim3(32, 8, 2), 128, 0, stream>>>(Qws, Kws, Vt, Ows);
    gemm_o_kernel<<<dim3(8, 64), 256, 0, stream>>>(Ows, Wo, bo, (float*)d_out);
}

// Round 11
// 167.949 us; speedup vs baseline: 1.2716x; 1.2716x over previous
//
#include <hip/hip_runtime.h>
#include <hip/hip_bf16.h>

typedef unsigned short ushort_t;
typedef __attribute__((ext_vector_type(8))) short bf16x8;
typedef __attribute__((ext_vector_type(4))) float f32x4;

__device__ __forceinline__ ushort_t f2bf(float f) {
    union { float f; unsigned u; } v; v.f = f;
    unsigned r = v.u + 0x7FFF + ((v.u >> 16) & 1);
    return (ushort_t)(r >> 16);
}
__device__ __forceinline__ bf16x8 ld8(const ushort_t* p) { return *(const bf16x8*)p; }

__device__ __forceinline__ unsigned cvt2(float x, float y) {
    __hip_bfloat162 h = __float22bfloat162_rn(make_float2(x, y));
    unsigned r; __builtin_memcpy(&r, &h, 4); return r;
}
__device__ __forceinline__ bf16x8 pack8f(float4 a, float4 b) {
    union { unsigned u[4]; bf16x8 v; } o;
    o.u[0] = cvt2(a.x, a.y); o.u[1] = cvt2(a.z, a.w);
    o.u[2] = cvt2(b.x, b.y); o.u[3] = cvt2(b.z, b.w);
    return o.v;
}

// ---------------------------------------------------------------------------
// Fused QKV projection. grid (4, 32, 3) = 384 blocks. 128x128 tile, BK=64,
// pipelined, A and W fp32 (in-register pack to bf16).
// z=0: Q*C1 bf16 [m][n]; z=1: K bf16 [m][n];
// z=2: V^T sigma-permuted bf16 via LDS-transpose epilogue (coalesced stores):
//      dst[((b*8+h)*64+d)*2048 + (s&~127) + 8*(s%16) + ((s>>4)&7)].
// LDS: 2 x 128x72 staging (36.9 KB); z==2 epilogue reuses it as 128x136 lT.
// ---------------------------------------------------------------------------
__global__ __launch_bounds__(256, 2)
void proj_qkv_kernel(const float* __restrict__ Qe, const float* __restrict__ Ke,
                     const float* __restrict__ x,
                     const float* __restrict__ Wq, const float* __restrict__ Wk,
                     const float* __restrict__ Wv,
                     const float* __restrict__ bq, const float* __restrict__ bk,
                     const float* __restrict__ bv,
                     ushort_t* __restrict__ Qo, ushort_t* __restrict__ Ko,
                     ushort_t* __restrict__ Vt)
{
    __shared__ ushort_t smem[2 * 128 * 72];      // lA | lB; reused as lT (128x136)
    ushort_t* lA = smem;
    ushort_t* lB = smem + 128 * 72;

    const int z = blockIdx.z;
    const float* A = (z == 0) ? Qe : (z == 1) ? Ke : x;
    const float* W = (z == 0) ? Wq : (z == 1) ? Wk : Wv;
    const float* bias = (z == 0) ? bq : (z == 1) ? bk : bv;

    const int m0 = blockIdx.y * 128, n0 = blockIdx.x * 128;
    const int t = threadIdx.x;
    const int lane = t & 63, wave = t >> 6;
    const int wm = (wave & 1) * 64, wn = (wave >> 1) * 64;
    const int fr = lane & 15, quad = lane >> 4;

    f32x4 acc[4][4] = {};
    float4 fa[4][2], fw[4][2];

    // prologue: loads for k0 = 0
#pragma unroll
    for (int i = 0; i < 4; ++i) {
        int s = i * 256 + t;
        int r = s >> 3, jp = s & 7;
        const float* pa = A + (size_t)(m0 + r) * 512 + jp * 8;
        fa[i][0] = *(const float4*)pa; fa[i][1] = *(const float4*)(pa + 4);
        const float* pw = W + (size_t)(n0 + r) * 512 + jp * 8;
        fw[i][0] = *(const float4*)pw; fw[i][1] = *(const float4*)(pw + 4);
    }

    for (int kk = 0; kk < 8; ++kk) {
        if (kk) __syncthreads();
#pragma unroll
        for (int i = 0; i < 4; ++i) {
            int s = i * 256 + t;
            int r = s >> 3, jp = s & 7;
            *(bf16x8*)(lA + r * 72 + jp * 8) = pack8f(fa[i][0], fa[i][1]);
            *(bf16x8*)(lB + r * 72 + jp * 8) = pack8f(fw[i][0], fw[i][1]);
        }
        __syncthreads();
        if (kk < 7) {
            int k0 = (kk + 1) * 64;
#pragma unroll
            for (int i = 0; i < 4; ++i) {
                int s = i * 256 + t;
                int r = s >> 3, jp = s & 7;
                const float* pa = A + (size_t)(m0 + r) * 512 + k0 + jp * 8;
                fa[i][0] = *(const float4*)pa; fa[i][1] = *(const float4*)(pa + 4);
                const float* pw = W + (size_t)(n0 + r) * 512 + k0 + jp * 8;
                fw[i][0] = *(const float4*)pw; fw[i][1] = *(const float4*)(pw + 4);
            }
        }

#pragma unroll
        for (int ks = 0; ks < 2; ++ks) {
            bf16x8 af[4], bfrag[4];
#pragma unroll
            for (int mt = 0; mt < 4; ++mt)
                af[mt] = ld8(lA + (wm + mt * 16 + fr) * 72 + (ks * 4 + quad) * 8);
#pragma unroll
            for (int nt = 0; nt < 4; ++nt)
                bfrag[nt] = ld8(lB + (wn + nt * 16 + fr) * 72 + (ks * 4 + quad) * 8);
#pragma unroll
            for (int mt = 0; mt < 4; ++mt)
#pragma unroll
                for (int nt = 0; nt < 4; ++nt)
                    acc[mt][nt] = __builtin_amdgcn_mfma_f32_16x16x32_bf16(
                        af[mt], bfrag[nt], acc[mt][nt], 0, 0, 0);
        }
    }

    const float C1 = 0.125f * 1.44269504088896340736f;
    // C/D: col = lane&15, row = quad*4 + reg (measured m89/m91).
    if (z != 2) {
        ushort_t* dst = (z == 0) ? Qo : Ko;
#pragma unroll
        for (int nt = 0; nt < 4; ++nt) {
            int n = n0 + wn + nt * 16 + fr;
            float bb = bias[n];
#pragma unroll
            for (int mt = 0; mt < 4; ++mt) {
                int mb = m0 + wm + mt * 16 + quad * 4;
                if (z == 0) {
#pragma unroll
                    for (int r = 0; r < 4; ++r)
                        dst[(size_t)(mb + r) * 512 + n] = f2bf((acc[mt][nt][r] + bb) * C1);
                } else {
#pragma unroll
                    for (int r = 0; r < 4; ++r)
                        dst[(size_t)(mb + r) * 512 + n] = f2bf(acc[mt][nt][r] + bb);
                }
            }
        }
    } else {
        // V^T epilogue: sigma-scatter into LDS, then coalesced b128 stores.
        __syncthreads();                  // all waves done reading lA/lB
        ushort_t* lT = smem;              // [n 0..127][sigma-token 0..127], stride 136
#pragma unroll
        for (int nt = 0; nt < 4; ++nt) {
            int nl = wn + nt * 16 + fr;
            float bb = bias[n0 + nl];
#pragma unroll
            for (int mt = 0; mt < 4; ++mt) {
                int tm = wm + mt * 16 + quad * 4;
#pragma unroll
                for (int r = 0; r < 4; ++r) {
                    int tl = tm + r;
                    int sg = 8 * (tl & 15) + ((tl >> 4) & 7);
                    lT[nl * 136 + sg] = f2bf(acc[mt][nt][r] + bb);
                }
            }
        }
        __syncthreads();
        const int bidx = m0 >> 11, m0t = m0 & 2047;
#pragma unroll
        for (int i = 0; i < 8; ++i) {
            int s = i * 256 + t;
            int row = s >> 4, c = s & 15;
            int n = n0 + row;
            int h = n >> 6, d = n & 63;
            bf16x8 v = ld8(lT + row * 136 + c * 8);
            *(bf16x8*)(Vt + ((size_t)((bidx * 8 + h) * 64 + d)) * 2048 + m0t + c * 8) = v;
        }
    }
}

// ---------------------------------------------------------------------------
// O-projection: 64x64 tile, grid (8,64) = 512 blocks (2/CU), BK=64, pipelined.
// A bf16, W fp32 (in-register pack).
// ---------------------------------------------------------------------------
__global__ __launch_bounds__(256, 2)
void gemm_o_kernel(const ushort_t* __restrict__ A, const float* __restrict__ W,
                   const float* __restrict__ bias, float* __restrict__ dst)
{
    __shared__ ushort_t lA[64 * 72];
    __shared__ ushort_t lB[64 * 72];
    const int m0 = blockIdx.y * 64, n0 = blockIdx.x * 64;
    const int t = threadIdx.x;
    const int lane = t & 63, wave = t >> 6;
    const int wm = (wave & 1) * 32, wn = (wave >> 1) * 32;
    const int fr = lane & 15, quad = lane >> 4;

    f32x4 acc[2][2] = {};
    bf16x8 va[2];
    float4 fw[2][2];

#pragma unroll
    for (int i = 0; i < 2; ++i) {
        int s = i * 256 + t;
        int r = s >> 3, jp = s & 7;
        va[i] = ld8(A + (size_t)(m0 + r) * 512 + jp * 8);
        const float* p = W + (size_t)(n0 + r) * 512 + jp * 8;
        fw[i][0] = *(const float4*)p; fw[i][1] = *(const float4*)(p + 4);
    }

    for (int kk = 0; kk < 8; ++kk) {
        if (kk) __syncthreads();
#pragma unroll
        for (int i = 0; i < 2; ++i) {
            int s = i * 256 + t;
            int r = s >> 3, jp = s & 7;
            *(bf16x8*)(lA + r * 72 + jp * 8) = va[i];
            *(bf16x8*)(lB + r * 72 + jp * 8) = pack8f(fw[i][0], fw[i][1]);
        }
        __syncthreads();
        if (kk < 7) {
            int k0 = (kk + 1) * 64;
#pragma unroll
            for (int i = 0; i < 2; ++i) {
                int s = i * 256 + t;
                int r = s >> 3, jp = s & 7;
                va[i] = ld8(A + (size_t)(m0 + r) * 512 + k0 + jp * 8);
                const float* p = W + (size_t)(n0 + r) * 512 + k0 + jp * 8;
                fw[i][0] = *(const float4*)p; fw[i][1] = *(const float4*)(p + 4);
            }
        }

        bf16x8 af[2][2], bfrag[2][2];
#pragma unroll
        for (int ks = 0; ks < 2; ++ks) {
#pragma unroll
            for (int mt = 0; mt < 2; ++mt)
                af[mt][ks] = ld8(lA + (wm + mt * 16 + fr) * 72 + (ks * 4 + quad) * 8);
#pragma unroll
            for (int nt = 0; nt < 2; ++nt)
                bfrag[nt][ks] = ld8(lB + (wn + nt * 16 + fr) * 72 + (ks * 4 + quad) * 8);
        }
#pragma unroll
        for (int ks = 0; ks < 2; ++ks)
#pragma unroll
            for (int mt = 0; mt < 2; ++mt)
#pragma unroll
                for (int nt = 0; nt < 2; ++nt)
                    acc[mt][nt] = __builtin_amdgcn_mfma_f32_16x16x32_bf16(
                        af[mt][ks], bfrag[nt][ks], acc[mt][nt], 0, 0, 0);
    }

#pragma unroll
    for (int nt = 0; nt < 2; ++nt) {
        int n = n0 + wn + nt * 16 + fr;
        float bb = bias[n];
#pragma unroll
        for (int mt = 0; mt < 2; ++mt) {
            int mb = m0 + wm + mt * 16 + quad * 4;
#pragma unroll
            for (int r = 0; r < 4; ++r)
                dst[(size_t)(mb + r) * 512 + n] = acc[mt][nt][r] + bb;
        }
    }
}

// ---------------------------------------------------------------------------
// Single-pass flash attention (r9 winner, verbatim): no-max softmax (C1 in Q),
// Q-frags in registers, 4 waves x 16 q-rows, grid (32,8,2) = 512 blocks
// (2 blocks/CU = 8 waves/CU), KV-tile 128, sigma key order in lP/lVt.
// ---------------------------------------------------------------------------
__global__ __launch_bounds__(256, 2)
void attn_kernel(const ushort_t* __restrict__ Q, const ushort_t* __restrict__ K,
                 const ushort_t* __restrict__ Vt, ushort_t* __restrict__ O)
{
    __shared__ ushort_t lK[128 * 72];
    __shared__ ushort_t lVt[64 * 136];   // [d][key-sigma]
    __shared__ ushort_t lP[64 * 136];    // [q][key-sigma], wave-local rows

    const int b = blockIdx.z, h = blockIdx.y;
    const int q0 = blockIdx.x * 64;
    const int t = threadIdx.x;
    const int lane = t & 63, wave = t >> 6;
    const int wq = wave * 16;
    const int fr = lane & 15, quad = lane >> 4;

    bf16x8 aq[2];
    {
        const ushort_t* qp = Q + (size_t)(b * 2048 + q0 + wq + fr) * 512 + h * 64 + quad * 8;
        aq[0] = ld8(qp);
        aq[1] = ld8(qp + 32);
    }

    f32x4 oacc[4] = {};
    float lpart[4] = {};
    bf16x8 vk[4], vv[4];

#pragma unroll
    for (int i = 0; i < 4; ++i) {
        int s = i * 256 + t;
        int r = s >> 3, jp = s & 7;
        vk[i] = ld8(K + (size_t)(b * 2048 + r) * 512 + h * 64 + jp * 8);
        int r2 = s >> 4, jp2 = s & 15;
        vv[i] = ld8(Vt + (size_t)((b * 8 + h) * 64 + r2) * 2048 + jp2 * 8);
    }

    for (int kv = 0; kv < 2048; kv += 128) {
        if (kv) __syncthreads();
#pragma unroll
        for (int i = 0; i < 4; ++i) {
            int s = i * 256 + t;
            int r = s >> 3, jp = s & 7;
            *(bf16x8*)(lK + r * 72 + jp * 8) = vk[i];
            int r2 = s >> 4, jp2 = s & 15;
            *(bf16x8*)(lVt + r2 * 136 + jp2 * 8) = vv[i];
        }
        __syncthreads();
        if (kv + 128 < 2048) {
            int kn = kv + 128;
#pragma unroll
            for (int i = 0; i < 4; ++i) {
                int s = i * 256 + t;
                int r = s >> 3, jp = s & 7;
                vk[i] = ld8(K + (size_t)(b * 2048 + kn + r) * 512 + h * 64 + jp * 8);
                int r2 = s >> 4, jp2 = s & 15;
                vv[i] = ld8(Vt + (size_t)((b * 8 + h) * 64 + r2) * 2048 + kn + jp2 * 8);
            }
        }

        f32x4 sc[8] = {};
#pragma unroll
        for (int ks = 0; ks < 2; ++ks)
#pragma unroll
            for (int nt = 0; nt < 8; ++nt) {
                bf16x8 kb = ld8(lK + (nt * 16 + fr) * 72 + (ks * 4 + quad) * 8);
                sc[nt] = __builtin_amdgcn_mfma_f32_16x16x32_bf16(aq[ks], kb, sc[nt], 0, 0, 0);
            }

#pragma unroll
        for (int r = 0; r < 4; ++r) {
            int row = wq + quad * 4 + r;
            float pv[8];
            float acc = 0.f;
#pragma unroll
            for (int nt = 0; nt < 8; ++nt) {
                pv[nt] = exp2f(sc[nt][r]);
                acc += pv[nt];
            }
            lpart[r] += acc;
            union { unsigned u[4]; bf16x8 v; } pu;
            pu.u[0] = cvt2(pv[0], pv[1]); pu.u[1] = cvt2(pv[2], pv[3]);
            pu.u[2] = cvt2(pv[4], pv[5]); pu.u[3] = cvt2(pv[6], pv[7]);
            *(bf16x8*)(lP + row * 136 + fr * 8) = pu.v;
        }

#pragma unroll
        for (int ks = 0; ks < 4; ++ks) {
            bf16x8 ap = ld8(lP + (wq + fr) * 136 + ks * 32 + quad * 8);
#pragma unroll
            for (int nt = 0; nt < 4; ++nt) {
                bf16x8 vb = ld8(lVt + (nt * 16 + fr) * 136 + ks * 32 + quad * 8);
                oacc[nt] = __builtin_amdgcn_mfma_f32_16x16x32_bf16(ap, vb, oacc[nt], 0, 0, 0);
            }
        }
    }

#pragma unroll
    for (int r = 0; r < 4; ++r) {
        float rs = lpart[r];
#pragma unroll
        for (int o = 1; o < 16; o <<= 1)
            rs += __shfl_xor(rs, o, 64);
        float inv = 1.f / rs;
        int q = q0 + wq + quad * 4 + r;
#pragma unroll
        for (int nt = 0; nt < 4; ++nt) {
            int d = nt * 16 + fr;
            O[(size_t)(b * 2048 + q) * 512 + h * 64 + d] = f2bf(oacc[nt][r] * inv);
        }
    }
}

extern "C" void kernel_launch(void* const* d_in, const int* in_sizes, int n_in,
                              void* d_out, int out_size, void* d_ws, size_t ws_size,
                              hipStream_t stream) {
    const float* x   = (const float*)d_in[0];
    const float* Qe  = (const float*)d_in[1];
    const float* Ke  = (const float*)d_in[2];
    // d_in[3..6] scalars unused (drofe_fn is None in reference)
    const float* Wq  = (const float*)d_in[7];
    const float* bq  = (const float*)d_in[8];
    const float* Wk  = (const float*)d_in[9];
    const float* bk  = (const float*)d_in[10];
    const float* Wv  = (const float*)d_in[11];
    const float* bv  = (const float*)d_in[12];
    const float* Wo  = (const float*)d_in[13];
    const float* bo  = (const float*)d_in[14];

    const size_t NTOK = 2 * 2048;
    const size_t ACT = NTOK * 512;

    ushort_t* p = (ushort_t*)d_ws;
    ushort_t* Qws = p; p += ACT;           // [B,S,512], pre-scaled by C1
    ushort_t* Kws = p; p += ACT;           // [B,S,512]
    ushort_t* Vt  = p; p += ACT;           // [B,H,64,S] sigma-permuted per 128
    ushort_t* Ows = p; p += ACT;           // [B,S,512]

    proj_qkv_kernel<<<dim3(4, 32, 3), 256, 0, stream>>>(Qe, Ke, x, Wq, Wk, Wv,
                                                        bq, bk, bv, Qws, Kws, Vt);
    attn_kernel<<<dim3(32, 8, 2), 256, 0, stream>>>(Qws, Kws, Vt, Ows);
    gemm_o_kernel<<<dim3(8, 64), 256, 0, stream>>>(Ows, Wo, bo, (float*)d_out);
}